// Round 1
// baseline (4050.446 us; speedup 1.0000x reference)
//
#include <hip/hip_runtime.h>
#include <hip/hip_bf16.h>

#define B_SZ   4096
#define NPC    32
#define NJ     100
#define CD     16
#define PD     8

// ---------------------------------------------------------------------------
// Generic fp32 tiled GEMM: C = relu(A[M,K] @ B[K,N] + bias), 64x64 tile, BK=16
// ---------------------------------------------------------------------------
__global__ __launch_bounds__(256) void gemm_bias_relu(
    const float* __restrict__ A, const float* __restrict__ Bm,
    const float* __restrict__ bias, float* __restrict__ C,
    int M, int N, int K)
{
    __shared__ float As[16][64];   // [k][m] (transposed for m-contiguous reads)
    __shared__ float Bs[16][64];   // [k][n]
    const int t  = threadIdx.x;
    const int tx = t & 15, ty = t >> 4;
    const int m0 = blockIdx.y * 64, n0 = blockIdx.x * 64;

    const int arow = t >> 2;           // 0..63 (m within tile)
    const int ak   = (t & 3) << 2;     // 0,4,8,12 (k within tile)
    const int bk   = t >> 4;           // 0..15 (k within tile)
    const int bn   = (t & 15) << 2;    // 0..60 (n within tile)

    const float* Aptr = A + (size_t)(m0 + arow) * K + ak;
    const float* Bptr = Bm + (size_t)bk * N + n0 + bn;

    float acc[4][4] = {};

    for (int k0 = 0; k0 < K; k0 += 16) {
        float4 av = *(const float4*)(Aptr + k0);
        float4 bv = *(const float4*)(Bptr + (size_t)k0 * N);
        As[ak + 0][arow] = av.x;
        As[ak + 1][arow] = av.y;
        As[ak + 2][arow] = av.z;
        As[ak + 3][arow] = av.w;
        *(float4*)&Bs[bk][bn] = bv;
        __syncthreads();
#pragma unroll
        for (int kk = 0; kk < 16; ++kk) {
            float4 a = *(const float4*)&As[kk][ty << 2];
            float4 b = *(const float4*)&Bs[kk][tx << 2];
            acc[0][0] += a.x * b.x; acc[0][1] += a.x * b.y; acc[0][2] += a.x * b.z; acc[0][3] += a.x * b.w;
            acc[1][0] += a.y * b.x; acc[1][1] += a.y * b.y; acc[1][2] += a.y * b.z; acc[1][3] += a.y * b.w;
            acc[2][0] += a.z * b.x; acc[2][1] += a.z * b.y; acc[2][2] += a.z * b.z; acc[2][3] += a.z * b.w;
            acc[3][0] += a.w * b.x; acc[3][1] += a.w * b.y; acc[3][2] += a.w * b.z; acc[3][3] += a.w * b.w;
        }
        __syncthreads();
    }

    float4 bb = *(const float4*)(bias + n0 + (tx << 2));
#pragma unroll
    for (int i = 0; i < 4; ++i) {
        size_t m = (size_t)m0 + (ty << 2) + i;
        float4 o;
        o.x = fmaxf(acc[i][0] + bb.x, 0.f);
        o.y = fmaxf(acc[i][1] + bb.y, 0.f);
        o.z = fmaxf(acc[i][2] + bb.z, 0.f);
        o.w = fmaxf(acc[i][3] + bb.w, 0.f);
        *(float4*)(C + m * N + n0 + (tx << 2)) = o;
    }
}

// ---------------------------------------------------------------------------
// LayerNorm over 256 features, 1 wave per row, 4 rows per block
// ---------------------------------------------------------------------------
__global__ __launch_bounds__(256) void layernorm256(
    const float* __restrict__ x, const float* __restrict__ g,
    const float* __restrict__ bta, float* __restrict__ y)
{
    const int w = threadIdx.x >> 6, lane = threadIdx.x & 63;
    const size_t row = (size_t)blockIdx.x * 4 + w;
    const float* xr = x + row * 256;
    float4 v = *(const float4*)(xr + lane * 4);
    float s  = v.x + v.y + v.z + v.w;
    float s2 = v.x * v.x + v.y * v.y + v.z * v.z + v.w * v.w;
#pragma unroll
    for (int off = 32; off; off >>= 1) {
        s  += __shfl_down(s, off);
        s2 += __shfl_down(s2, off);
    }
    s  = __shfl(s, 0);
    s2 = __shfl(s2, 0);
    float mu   = s * (1.f / 256.f);
    float var  = s2 * (1.f / 256.f) - mu * mu;
    float rstd = rsqrtf(var + 1e-5f);
    float4 gg = *(const float4*)(g + lane * 4);
    float4 bb = *(const float4*)(bta + lane * 4);
    float4 o;
    o.x = (v.x - mu) * rstd * gg.x + bb.x;
    o.y = (v.y - mu) * rstd * gg.y + bb.y;
    o.z = (v.z - mu) * rstd * gg.z + bb.z;
    o.w = (v.w - mu) * rstd * gg.w + bb.w;
    *(float4*)(y + row * 256 + lane * 4) = o;
}

// ---------------------------------------------------------------------------
// Primary caps: prim[b,n,d] = LN_d( h[b,:] @ pc_W[n,:,d] + pc_b[n,d] ) * g + beta
// One block per batch element; thread t = (n=t/8, d=t%8)
// ---------------------------------------------------------------------------
__global__ __launch_bounds__(256) void prim_caps(
    const float* __restrict__ h, const float* __restrict__ pcW,
    const float* __restrict__ pcB, const float* __restrict__ pcG,
    const float* __restrict__ pcBeta, float* __restrict__ prim)
{
    __shared__ float hs[256];
    __shared__ float tmp[256];
    const int t = threadIdx.x;
    const size_t b = blockIdx.x;
    hs[t] = h[b * 256 + t];
    __syncthreads();
    const int n = t >> 3, d = t & 7;
    const float* wp = pcW + n * 256 * 8 + d;
    float acc = pcB[t];
#pragma unroll 4
    for (int k = 0; k < 256; ++k) acc += hs[k] * wp[k * 8];
    tmp[t] = acc;
    __syncthreads();
    float mu = 0.f, s2 = 0.f;
    const int base = n << 3;
#pragma unroll
    for (int q = 0; q < 8; ++q) {
        float xx = tmp[base + q];
        mu += xx;
        s2 += xx * xx;
    }
    mu *= 0.125f;
    s2 = s2 * 0.125f - mu * mu;
    float rstd = rsqrtf(s2 + 1e-5f);
    prim[b * 256 + t] = (acc - mu) * rstd * pcG[t] + pcBeta[t];
}

// ---------------------------------------------------------------------------
// Dynamic routing: one block handles 2 batch elements (TB=2).
// pred recomputed on the fly from prim (LDS) and dc_W (L2-resident).
// ---------------------------------------------------------------------------
__global__ __launch_bounds__(256) void routing_kernel(
    const float* __restrict__ prim,          // [B,32,8]
    const float* __restrict__ slot_features, // [B,100]
    const float* __restrict__ slot_priors,   // [100,100]
    const float* __restrict__ dcW,           // [32,100,16,8]
    const float* __restrict__ targets,       // [100,16]
    const float* __restrict__ temp_p,
    float* __restrict__ out)                 // [B,100]
{
    __shared__ float prim2[2][256];
    __shared__ float sp2[2][NJ];
    __shared__ float bst[2][NPC * NJ];
    __shared__ float sv[2][NJ * CD];
    __shared__ float rm[2][NPC];
    __shared__ float irs[2][NPC];
    __shared__ float red[256];
    __shared__ float ssum[2];

    const int t = threadIdx.x;
    const int b0 = blockIdx.x * 2;

    // P0: load prim rows
    prim2[0][t] = prim[(size_t)b0 * 256 + t];
    prim2[1][t] = prim[(size_t)(b0 + 1) * 256 + t];

    // P1: slot feature relu
    if (t < 100)                    red[t] = fmaxf(slot_features[(size_t)b0 * 100 + t], 0.f);
    else if (t >= 128 && t < 228)   red[t] = fmaxf(slot_features[(size_t)(b0 + 1) * 100 + (t - 128)], 0.f);
    __syncthreads();
    if (t < 2) {
        float s = 0.f;
        const int base = t * 128;
        for (int k = 0; k < 100; ++k) s += red[base + k];
        ssum[t] = fmaxf(s, 1e-6f);
    }
    __syncthreads();
    // sp[j] = sum_k (relu/sum - 1/NJ) * slot_priors[k,j]
    {
        int bl = -1, j = 0;
        if (t < 100) { bl = 0; j = t; }
        else if (t >= 128 && t < 228) { bl = 1; j = t - 128; }
        if (bl >= 0) {
            const float inv = 1.f / ssum[bl];
            const int base = bl * 128;
            float acc = 0.f;
            for (int k = 0; k < 100; ++k) {
                float w = red[base + k] * inv - (1.f / NJ);
                acc += w * slot_priors[k * NJ + j];
            }
            sp2[bl][j] = acc;
        }
    }
    __syncthreads();
    // P2: b-state init: b = sp * PRIOR_STRENGTH
    for (int idx = t; idx < 2 * NPC * NJ; idx += 256) {
        int bl = idx / (NPC * NJ);
        int r  = idx % (NPC * NJ);
        bst[bl][r] = sp2[bl][r % NJ] * 0.1f;
    }
    __syncthreads();

    for (int it = 0; it < 3; ++it) {
        // softmax row stats over j per (bl,n): 64 rows x 4 threads
        {
            const int row = t >> 2, q = t & 3;
            const int bl = row >> 5, n = row & 31;
            float m = -1e30f;
            for (int j = q; j < NJ; j += 4) m = fmaxf(m, bst[bl][n * NJ + j]);
            red[t] = m;
            __syncthreads();
            if (q == 0) rm[bl][n] = fmaxf(fmaxf(red[t], red[t + 1]), fmaxf(red[t + 2], red[t + 3]));
            __syncthreads();
            const float rmv = rm[bl][n];
            float s = 0.f;
            for (int j = q; j < NJ; j += 4) s += __expf(bst[bl][n * NJ + j] - rmv);
            red[t] = s;
            __syncthreads();
            if (q == 0) irs[bl][n] = 1.f / (red[t] + red[t + 1] + red[t + 2] + red[t + 3]);
            __syncthreads();
        }
        // s-pass + squash: thread (bl = t&1, j = t>>1), t < 200
        if (t < 200) {
            const int bl = t & 1, j = t >> 1;
            float sacc[CD];
#pragma unroll
            for (int o = 0; o < CD; ++o) sacc[o] = 0.f;
            const float* pb = prim2[bl];
            for (int n = 0; n < NPC; ++n) {
                const float cc = __expf(bst[bl][n * NJ + j] - rm[bl][n]) * irs[bl][n];
                const float4* wp = (const float4*)(dcW + (size_t)(n * NJ + j) * (CD * PD));
                const float p0 = pb[n * 8 + 0], p1 = pb[n * 8 + 1], p2 = pb[n * 8 + 2], p3 = pb[n * 8 + 3];
                const float p4 = pb[n * 8 + 4], p5 = pb[n * 8 + 5], p6 = pb[n * 8 + 6], p7 = pb[n * 8 + 7];
#pragma unroll
                for (int o = 0; o < CD; ++o) {
                    float4 w0 = wp[o * 2];
                    float4 w1 = wp[o * 2 + 1];
                    float pr = w0.x * p0 + w0.y * p1 + w0.z * p2 + w0.w * p3
                             + w1.x * p4 + w1.y * p5 + w1.z * p6 + w1.w * p7;
                    sacc[o] += cc * pr;
                }
            }
            float sq = 0.f;
#pragma unroll
            for (int o = 0; o < CD; ++o) sq += sacc[o] * sacc[o];
            const float f = (sq / (1.f + sq)) / sqrtf(sq + 1e-8f);
#pragma unroll
            for (int o = 0; o < CD; ++o) sv[bl][j * CD + o] = f * sacc[o];
        }
        __syncthreads();
        // a-pass: b += sum_o pred*v + sp*strength
        if (it < 2) {
            const float str = 0.1f - 0.02f * (float)(it + 1);
            for (int idx = t; idx < 2 * NPC * NJ; idx += 256) {
                const int bl = idx & 1;
                const int r = idx >> 1;           // 0..3199
                const int n = r / NJ, j = r % NJ;
                const float4* wp = (const float4*)(dcW + (size_t)(n * NJ + j) * (CD * PD));
                const float* pb = &prim2[bl][n * 8];
                const float p0 = pb[0], p1 = pb[1], p2 = pb[2], p3 = pb[3];
                const float p4 = pb[4], p5 = pb[5], p6 = pb[6], p7 = pb[7];
                float a = 0.f;
#pragma unroll
                for (int o = 0; o < CD; ++o) {
                    float4 w0 = wp[o * 2];
                    float4 w1 = wp[o * 2 + 1];
                    float pr = w0.x * p0 + w0.y * p1 + w0.z * p2 + w0.w * p3
                             + w1.x * p4 + w1.y * p5 + w1.z * p6 + w1.w * p7;
                    a += pr * sv[bl][j * CD + o];
                }
                bst[bl][n * NJ + j] += a + sp2[bl][j] * str;
            }
            __syncthreads();
        }
    }

    // final: l2norm + logits
    if (t < 200) {
        const int bl = t & 1, j = t >> 1;
        float sqn = 0.f;
#pragma unroll
        for (int o = 0; o < CD; ++o) {
            float v = sv[bl][j * CD + o];
            sqn += v * v;
        }
        const float inv = 1.f / fmaxf(sqrtf(sqn), 1e-12f);
        const float T = *temp_p;
        float lg = 0.f;
#pragma unroll
        for (int o = 0; o < CD; ++o)
            lg += sv[bl][j * CD + o] * inv * targets[j * CD + o];
        out[(size_t)(b0 + bl) * NJ + j] = lg * T;
    }
}

// ---------------------------------------------------------------------------
extern "C" void kernel_launch(void* const* d_in, const int* in_sizes, int n_in,
                              void* d_out, int out_size, void* d_ws, size_t ws_size,
                              hipStream_t stream)
{
    const float* features      = (const float*)d_in[0];   // 4096 x 20000
    const float* slot_features = (const float*)d_in[1];   // 4096 x 100
    const float* W1            = (const float*)d_in[2];   // 20000 x 512
    const float* b1            = (const float*)d_in[3];   // 512
    const float* W2            = (const float*)d_in[4];   // 512 x 256
    const float* b2            = (const float*)d_in[5];   // 256
    const float* ln_g          = (const float*)d_in[6];   // 256
    const float* ln_b          = (const float*)d_in[7];   // 256
    const float* pc_W          = (const float*)d_in[8];   // 32 x 256 x 8
    const float* pc_b          = (const float*)d_in[9];   // 32 x 8
    const float* pc_g          = (const float*)d_in[10];  // 32 x 8
    const float* pc_beta       = (const float*)d_in[11];  // 32 x 8
    const float* dc_W          = (const float*)d_in[12];  // 32 x 100 x 16 x 8
    const float* slot_priors   = (const float*)d_in[13];  // 100 x 100
    const float* targets       = (const float*)d_in[14];  // 100 x 16
    const float* temperature   = (const float*)d_in[15];  // 1
    float* out = (float*)d_out;

    float* h1 = (float*)d_ws;                 // 4096*512
    float* h2 = h1 + (size_t)B_SZ * 512;      // 4096*256
    float* h  = h2 + (size_t)B_SZ * 256;      // 4096*256
    float* pr = h  + (size_t)B_SZ * 256;      // 4096*256

    // h1 = relu(features @ W1 + b1)
    gemm_bias_relu<<<dim3(512 / 64, B_SZ / 64), 256, 0, stream>>>(
        features, W1, b1, h1, B_SZ, 512, 20000);
    // h2 = relu(h1 @ W2 + b2)
    gemm_bias_relu<<<dim3(256 / 64, B_SZ / 64), 256, 0, stream>>>(
        h1, W2, b2, h2, B_SZ, 256, 512);
    // h = layernorm(h2)
    layernorm256<<<B_SZ / 4, 256, 0, stream>>>(h2, ln_g, ln_b, h);
    // prim caps + per-cap layernorm
    prim_caps<<<B_SZ, 256, 0, stream>>>(h, pc_W, pc_b, pc_g, pc_beta, pr);
    // routing + logits
    routing_kernel<<<B_SZ / 2, 256, 0, stream>>>(
        pr, slot_features, slot_priors, dc_W, targets, temperature, out);
}

// Round 2
// 2523.802 us; speedup vs baseline: 1.6049x; 1.6049x over previous
//
#include <hip/hip_runtime.h>
#include <hip/hip_bf16.h>

#define B_SZ   4096
#define NPC    32
#define NJ     100
#define CD     16
#define PD     8

__device__ __forceinline__ void outer4(float (&acc)[4][4], float4 a, float4 b) {
    acc[0][0] += a.x * b.x; acc[0][1] += a.x * b.y; acc[0][2] += a.x * b.z; acc[0][3] += a.x * b.w;
    acc[1][0] += a.y * b.x; acc[1][1] += a.y * b.y; acc[1][2] += a.y * b.z; acc[1][3] += a.y * b.w;
    acc[2][0] += a.z * b.x; acc[2][1] += a.z * b.y; acc[2][2] += a.z * b.z; acc[2][3] += a.z * b.w;
    acc[3][0] += a.w * b.x; acc[3][1] += a.w * b.y; acc[3][2] += a.w * b.z; acc[3][3] += a.w * b.w;
}

// ---------------------------------------------------------------------------
// GEMM1: C += A[M,K] @ B[K,N], 128x128 tile, split-K=4, atomicAdd epilogue.
// Bias+ReLU deferred to gemm2's A staging.
// ---------------------------------------------------------------------------
__global__ __launch_bounds__(256) void gemm1_splitk(
    const float* __restrict__ A, const float* __restrict__ Bm,
    float* __restrict__ C, int M, int N, int K)
{
    __shared__ float As[16][132];
    __shared__ float Bs[16][132];
    const int t  = threadIdx.x;
    const int tx = t & 15, ty = t >> 4;
    const int n0 = blockIdx.x * 128, m0 = blockIdx.y * 128;
    const int ks = blockIdx.z * 5008;
    const int ke = min(ks + 5008, K);

    const int arow = t >> 1, ak8 = (t & 1) * 8;
    const int bk = t >> 4, bn8 = (t & 15) * 8;

    const float* Ap = A + (size_t)(m0 + arow) * K + ak8;
    const float* Bp = Bm + (size_t)bk * N + n0 + bn8;

    float acc[2][2][4][4] = {};

    for (int k0 = ks; k0 < ke; k0 += 16) {
        float4 a0  = *(const float4*)(Ap + k0);
        float4 a1  = *(const float4*)(Ap + k0 + 4);
        float4 bv0 = *(const float4*)(Bp + (size_t)k0 * N);
        float4 bv1 = *(const float4*)(Bp + (size_t)k0 * N + 4);
        As[ak8 + 0][arow] = a0.x; As[ak8 + 1][arow] = a0.y;
        As[ak8 + 2][arow] = a0.z; As[ak8 + 3][arow] = a0.w;
        As[ak8 + 4][arow] = a1.x; As[ak8 + 5][arow] = a1.y;
        As[ak8 + 6][arow] = a1.z; As[ak8 + 7][arow] = a1.w;
        *(float4*)&Bs[bk][bn8]     = bv0;
        *(float4*)&Bs[bk][bn8 + 4] = bv1;
        __syncthreads();
#pragma unroll
        for (int kk = 0; kk < 16; ++kk) {
            float4 aa0 = *(const float4*)&As[kk][ty * 4];
            float4 aa1 = *(const float4*)&As[kk][64 + ty * 4];
            float4 bb0 = *(const float4*)&Bs[kk][tx * 4];
            float4 bb1 = *(const float4*)&Bs[kk][64 + tx * 4];
            outer4(acc[0][0], aa0, bb0);
            outer4(acc[0][1], aa0, bb1);
            outer4(acc[1][0], aa1, bb0);
            outer4(acc[1][1], aa1, bb1);
        }
        __syncthreads();
    }
#pragma unroll
    for (int ri = 0; ri < 2; ++ri)
#pragma unroll
    for (int r = 0; r < 4; ++r) {
        const size_t row = (size_t)m0 + ri * 64 + ty * 4 + r;
        float* Cp = C + row * N + n0;
#pragma unroll
        for (int ci = 0; ci < 2; ++ci) {
            const int col = ci * 64 + tx * 4;
            atomicAdd(&Cp[col + 0], acc[ri][ci][r][0]);
            atomicAdd(&Cp[col + 1], acc[ri][ci][r][1]);
            atomicAdd(&Cp[col + 2], acc[ri][ci][r][2]);
            atomicAdd(&Cp[col + 3], acc[ri][ci][r][3]);
        }
    }
}

// ---------------------------------------------------------------------------
// GEMM2: C = relu( relu(A + b1) @ B + b2 ), 64x64 tile (A = raw gemm1 sums)
// ---------------------------------------------------------------------------
__global__ __launch_bounds__(256) void gemm2_fused(
    const float* __restrict__ A, const float* __restrict__ b1v,
    const float* __restrict__ Bm, const float* __restrict__ bias,
    float* __restrict__ C, int M, int N, int K)
{
    __shared__ float As[16][68];
    __shared__ float Bs[16][64];
    const int t  = threadIdx.x;
    const int tx = t & 15, ty = t >> 4;
    const int m0 = blockIdx.y * 64, n0 = blockIdx.x * 64;

    const int arow = t >> 2;
    const int ak   = (t & 3) << 2;
    const int bk   = t >> 4;
    const int bn   = (t & 15) << 2;

    const float* Aptr = A + (size_t)(m0 + arow) * K + ak;
    const float* Bptr = Bm + (size_t)bk * N + n0 + bn;

    float acc[4][4] = {};

    for (int k0 = 0; k0 < K; k0 += 16) {
        float4 av = *(const float4*)(Aptr + k0);
        float4 b1q = *(const float4*)(b1v + k0 + ak);
        av.x = fmaxf(av.x + b1q.x, 0.f);
        av.y = fmaxf(av.y + b1q.y, 0.f);
        av.z = fmaxf(av.z + b1q.z, 0.f);
        av.w = fmaxf(av.w + b1q.w, 0.f);
        float4 bv = *(const float4*)(Bptr + (size_t)k0 * N);
        As[ak + 0][arow] = av.x;
        As[ak + 1][arow] = av.y;
        As[ak + 2][arow] = av.z;
        As[ak + 3][arow] = av.w;
        *(float4*)&Bs[bk][bn] = bv;
        __syncthreads();
#pragma unroll
        for (int kk = 0; kk < 16; ++kk) {
            float4 a = *(const float4*)&As[kk][ty << 2];
            float4 b = *(const float4*)&Bs[kk][tx << 2];
            outer4(acc, a, b);
        }
        __syncthreads();
    }

    float4 bb = *(const float4*)(bias + n0 + (tx << 2));
#pragma unroll
    for (int i = 0; i < 4; ++i) {
        size_t m = (size_t)m0 + (ty << 2) + i;
        float4 o;
        o.x = fmaxf(acc[i][0] + bb.x, 0.f);
        o.y = fmaxf(acc[i][1] + bb.y, 0.f);
        o.z = fmaxf(acc[i][2] + bb.z, 0.f);
        o.w = fmaxf(acc[i][3] + bb.w, 0.f);
        *(float4*)(C + m * N + n0 + (tx << 2)) = o;
    }
}

// ---------------------------------------------------------------------------
// LayerNorm over 256 features, 1 wave per row, 4 rows per block
// ---------------------------------------------------------------------------
__global__ __launch_bounds__(256) void layernorm256(
    const float* __restrict__ x, const float* __restrict__ g,
    const float* __restrict__ bta, float* __restrict__ y)
{
    const int w = threadIdx.x >> 6, lane = threadIdx.x & 63;
    const size_t row = (size_t)blockIdx.x * 4 + w;
    const float* xr = x + row * 256;
    float4 v = *(const float4*)(xr + lane * 4);
    float s  = v.x + v.y + v.z + v.w;
    float s2 = v.x * v.x + v.y * v.y + v.z * v.z + v.w * v.w;
#pragma unroll
    for (int off = 32; off; off >>= 1) {
        s  += __shfl_down(s, off);
        s2 += __shfl_down(s2, off);
    }
    s  = __shfl(s, 0);
    s2 = __shfl(s2, 0);
    float mu   = s * (1.f / 256.f);
    float var  = s2 * (1.f / 256.f) - mu * mu;
    float rstd = rsqrtf(var + 1e-5f);
    float4 gg = *(const float4*)(g + lane * 4);
    float4 bb = *(const float4*)(bta + lane * 4);
    float4 o;
    o.x = (v.x - mu) * rstd * gg.x + bb.x;
    o.y = (v.y - mu) * rstd * gg.y + bb.y;
    o.z = (v.z - mu) * rstd * gg.z + bb.z;
    o.w = (v.w - mu) * rstd * gg.w + bb.w;
    *(float4*)(y + row * 256 + lane * 4) = o;
}

// ---------------------------------------------------------------------------
// Primary caps: prim[b,n,d] = LN_d( h[b,:] @ pc_W[n,:,d] + pc_b[n,d] ) * g + beta
// ---------------------------------------------------------------------------
__global__ __launch_bounds__(256) void prim_caps(
    const float* __restrict__ h, const float* __restrict__ pcW,
    const float* __restrict__ pcB, const float* __restrict__ pcG,
    const float* __restrict__ pcBeta, float* __restrict__ prim)
{
    __shared__ float hs[256];
    __shared__ float tmp[256];
    const int t = threadIdx.x;
    const size_t b = blockIdx.x;
    hs[t] = h[b * 256 + t];
    __syncthreads();
    const int n = t >> 3, d = t & 7;
    const float* wp = pcW + n * 256 * 8 + d;
    float acc = pcB[t];
#pragma unroll 4
    for (int k = 0; k < 256; ++k) acc += hs[k] * wp[k * 8];
    tmp[t] = acc;
    __syncthreads();
    float mu = 0.f, s2 = 0.f;
    const int base = n << 3;
#pragma unroll
    for (int q = 0; q < 8; ++q) {
        float xx = tmp[base + q];
        mu += xx;
        s2 += xx * xx;
    }
    mu *= 0.125f;
    s2 = s2 * 0.125f - mu * mu;
    float rstd = rsqrtf(s2 + 1e-5f);
    prim[b * 256 + t] = (acc - mu) * rstd * pcG[t] + pcBeta[t];
}

// ---------------------------------------------------------------------------
// Dynamic routing, TB=4 batch rows per block. b-state bf16 in LDS,
// sv padded to stride 17 (conflict-free). s-pass: thread = (j, o-half).
// ---------------------------------------------------------------------------
__global__ __launch_bounds__(256) void routing4(
    const float* __restrict__ prim,          // [B,32,8]
    const float* __restrict__ sf,            // [B,100]
    const float* __restrict__ priors,        // [100,100]
    const float* __restrict__ dcW,           // [32,100,16,8]
    const float* __restrict__ targets,       // [100,16]
    const float* __restrict__ temp_p,
    float* __restrict__ out)                 // [B,100]
{
    __shared__ float prim2[4][256];
    __shared__ __hip_bfloat16 bstb[4][NPC * NJ];
    __shared__ float sv[4][NJ * 17];
    __shared__ float sp4[4][NJ];
    __shared__ float rm4[4][NPC];
    __shared__ float irs4[4][NPC];
    __shared__ float red[256];
    __shared__ float ssum[4];

    const int t = threadIdx.x;
    const int b0 = blockIdx.x << 2;

#pragma unroll
    for (int b = 0; b < 4; ++b)
        prim2[b][t] = prim[(size_t)(b0 + b) * 256 + t];

    // slot-prior pass (scratch in sv area, overwritten later)
    float* scr = &sv[0][0];
    for (int idx = t; idx < 400; idx += 256) {
        int b = idx / 100, k = idx - b * 100;
        scr[idx] = fmaxf(sf[(size_t)(b0 + b) * 100 + k], 0.f);
    }
    __syncthreads();
    if (t < 4) {
        float s = 0.f;
        for (int k = 0; k < 100; ++k) s += scr[t * 100 + k];
        ssum[t] = fmaxf(s, 1e-6f);
    }
    __syncthreads();
    for (int idx = t; idx < 400; idx += 256) {
        int b = idx / 100, j = idx - b * 100;
        const float inv = 1.f / ssum[b];
        float acc = 0.f;
        for (int k = 0; k < 100; ++k)
            acc += (scr[b * 100 + k] * inv - 0.01f) * priors[k * 100 + j];
        sp4[b][j] = acc;
    }
    __syncthreads();
    // b-state init
    for (int idx = t; idx < 4 * NPC * NJ; idx += 256) {
        int b = idx / (NPC * NJ);
        int r = idx - b * (NPC * NJ);
        int j = r % NJ;
        bstb[b][r] = __float2bfloat16(sp4[b][j] * 0.1f);
    }
    __syncthreads();

    for (int it = 0; it < 3; ++it) {
        // ---- softmax row stats over j per (b,n): 128 rows x 2 threads ----
        {
            const int row = t >> 1, q = t & 1;
            const int b = row >> 5, n = row & 31;
            const int base = n * NJ + q * 50;
            float m = -1e30f;
            for (int k = 0; k < 50; ++k)
                m = fmaxf(m, __bfloat162float(bstb[b][base + k]));
            red[t] = m;
            __syncthreads();
            if (q == 0) rm4[b][n] = fmaxf(red[t], red[t + 1]);
            __syncthreads();
            const float rmv = rm4[b][n];
            float s = 0.f;
            for (int k = 0; k < 50; ++k)
                s += __expf(__bfloat162float(bstb[b][base + k]) - rmv);
            red[t] = s;
            __syncthreads();
            if (q == 0) irs4[b][n] = 1.f / (red[t] + red[t + 1]);
            __syncthreads();
        }
        // ---- s-pass + squash: thread = (j = t>>1, oh = t&1), t < 200 ----
        if (t < 200) {
            const int j = t >> 1, oh = t & 1;
            float sacc[4][8];
#pragma unroll
            for (int b = 0; b < 4; ++b)
#pragma unroll
                for (int o = 0; o < 8; ++o) sacc[b][o] = 0.f;

            for (int n = 0; n < NPC; ++n) {
                float pv[4][8], cb[4];
#pragma unroll
                for (int b = 0; b < 4; ++b) {
                    float4 p0 = *(const float4*)&prim2[b][n * 8];
                    float4 p1 = *(const float4*)&prim2[b][n * 8 + 4];
                    pv[b][0] = p0.x; pv[b][1] = p0.y; pv[b][2] = p0.z; pv[b][3] = p0.w;
                    pv[b][4] = p1.x; pv[b][5] = p1.y; pv[b][6] = p1.z; pv[b][7] = p1.w;
                    cb[b] = __expf(__bfloat162float(bstb[b][n * NJ + j]) - rm4[b][n]) * irs4[b][n];
                }
                const float4* wp = (const float4*)(dcW + (size_t)((n * NJ + j) * CD + oh * 8) * PD);
#pragma unroll
                for (int o = 0; o < 8; ++o) {
                    float4 w0 = wp[2 * o], w1 = wp[2 * o + 1];
#pragma unroll
                    for (int b = 0; b < 4; ++b) {
                        float pr = w0.x * pv[b][0] + w0.y * pv[b][1] + w0.z * pv[b][2] + w0.w * pv[b][3]
                                 + w1.x * pv[b][4] + w1.y * pv[b][5] + w1.z * pv[b][6] + w1.w * pv[b][7];
                        sacc[b][o] += cb[b] * pr;
                    }
                }
            }
#pragma unroll
            for (int b = 0; b < 4; ++b) {
                float sq = 0.f;
#pragma unroll
                for (int o = 0; o < 8; ++o) sq += sacc[b][o] * sacc[b][o];
                sq += __shfl_xor(sq, 1);
                const float f = (sq / (1.f + sq)) / sqrtf(sq + 1e-8f);
#pragma unroll
                for (int o = 0; o < 8; ++o)
                    sv[b][j * 17 + oh * 8 + o] = f * sacc[b][o];
            }
        }
        __syncthreads();
        // ---- a-pass: all 256 threads over (n,j) pairs ----
        if (it < 2) {
            const float str = 0.1f - 0.02f * (float)(it + 1);
            for (int r = t; r < NPC * NJ; r += 256) {
                const int n = r / NJ, j = r - n * NJ;
                const float4* wp = (const float4*)(dcW + (size_t)r * (CD * PD));
                float pv[4][8];
#pragma unroll
                for (int b = 0; b < 4; ++b) {
                    float4 p0 = *(const float4*)&prim2[b][n * 8];
                    float4 p1 = *(const float4*)&prim2[b][n * 8 + 4];
                    pv[b][0] = p0.x; pv[b][1] = p0.y; pv[b][2] = p0.z; pv[b][3] = p0.w;
                    pv[b][4] = p1.x; pv[b][5] = p1.y; pv[b][6] = p1.z; pv[b][7] = p1.w;
                }
                float a[4] = {0.f, 0.f, 0.f, 0.f};
#pragma unroll
                for (int o = 0; o < CD; ++o) {
                    float4 w0 = wp[2 * o], w1 = wp[2 * o + 1];
#pragma unroll
                    for (int b = 0; b < 4; ++b) {
                        float pr = w0.x * pv[b][0] + w0.y * pv[b][1] + w0.z * pv[b][2] + w0.w * pv[b][3]
                                 + w1.x * pv[b][4] + w1.y * pv[b][5] + w1.z * pv[b][6] + w1.w * pv[b][7];
                        a[b] += pr * sv[b][j * 17 + o];
                    }
                }
#pragma unroll
                for (int b = 0; b < 4; ++b)
                    bstb[b][r] = __float2bfloat16(
                        __bfloat162float(bstb[b][r]) + a[b] + sp4[b][j] * str);
            }
            __syncthreads();
        }
    }
    __syncthreads();

    // ---- final: l2norm + logits ----
    const float T = *temp_p;
    for (int idx = t; idx < 400; idx += 256) {
        const int b = idx / 100, j = idx - b * 100;
        float sq = 0.f, lg = 0.f;
#pragma unroll
        for (int o = 0; o < CD; ++o) {
            float v = sv[b][j * 17 + o];
            sq += v * v;
            lg += v * targets[j * CD + o];
        }
        out[(size_t)(b0 + b) * NJ + j] = lg * T / fmaxf(sqrtf(sq), 1e-12f);
    }
}

// ---------------------------------------------------------------------------
extern "C" void kernel_launch(void* const* d_in, const int* in_sizes, int n_in,
                              void* d_out, int out_size, void* d_ws, size_t ws_size,
                              hipStream_t stream)
{
    const float* features      = (const float*)d_in[0];   // 4096 x 20000
    const float* slot_features = (const float*)d_in[1];   // 4096 x 100
    const float* W1            = (const float*)d_in[2];   // 20000 x 512
    const float* b1            = (const float*)d_in[3];   // 512
    const float* W2            = (const float*)d_in[4];   // 512 x 256
    const float* b2            = (const float*)d_in[5];   // 256
    const float* ln_g          = (const float*)d_in[6];   // 256
    const float* ln_b          = (const float*)d_in[7];   // 256
    const float* pc_W          = (const float*)d_in[8];   // 32 x 256 x 8
    const float* pc_b          = (const float*)d_in[9];   // 32 x 8
    const float* pc_g          = (const float*)d_in[10];  // 32 x 8
    const float* pc_beta       = (const float*)d_in[11];  // 32 x 8
    const float* dc_W          = (const float*)d_in[12];  // 32 x 100 x 16 x 8
    const float* slot_priors   = (const float*)d_in[13];  // 100 x 100
    const float* targets       = (const float*)d_in[14];  // 100 x 16
    const float* temperature   = (const float*)d_in[15];  // 1
    float* out = (float*)d_out;

    float* h1 = (float*)d_ws;                 // 4096*512 (raw, pre-bias/relu)
    float* h2 = h1 + (size_t)B_SZ * 512;      // 4096*256
    float* h  = h2 + (size_t)B_SZ * 256;      // 4096*256
    float* pr = h  + (size_t)B_SZ * 256;      // 4096*256

    hipMemsetAsync(h1, 0, (size_t)B_SZ * 512 * sizeof(float), stream);

    // h1 += features @ W1  (split-K=4, atomic)
    gemm1_splitk<<<dim3(512 / 128, B_SZ / 128, 4), 256, 0, stream>>>(
        features, W1, h1, B_SZ, 512, 20000);
    // h2 = relu( relu(h1 + b1) @ W2 + b2 )
    gemm2_fused<<<dim3(256 / 64, B_SZ / 64), 256, 0, stream>>>(
        h1, b1, W2, b2, h2, B_SZ, 256, 512);
    // h = layernorm(h2)
    layernorm256<<<B_SZ / 4, 256, 0, stream>>>(h2, ln_g, ln_b, h);
    // prim caps + per-cap layernorm
    prim_caps<<<B_SZ, 256, 0, stream>>>(h, pc_W, pc_b, pc_g, pc_beta, pr);
    // routing + logits (4 batch rows per block)
    routing4<<<B_SZ / 4, 256, 0, stream>>>(
        pr, slot_features, slot_priors, dc_W, targets, temperature, out);
}

// Round 3
// 1698.011 us; speedup vs baseline: 2.3854x; 1.4863x over previous
//
#include <hip/hip_runtime.h>
#include <hip/hip_bf16.h>

#define B_SZ   4096
#define NPC    32
#define NJ     100
#define CD     16
#define PD     8

typedef float  f32x4  __attribute__((ext_vector_type(4)));
typedef __bf16 bf16x8 __attribute__((ext_vector_type(8)));

__device__ __forceinline__ unsigned short f2bfr(float f) {
    union { float f; unsigned u; } v; v.f = f;
    return (unsigned short)((v.u + 0x8000u) >> 16);   // round-half-up to bf16
}
__device__ __forceinline__ float bf_lo(unsigned u) {
    union { unsigned u; float f; } v; v.u = u << 16; return v.f;
}
__device__ __forceinline__ float bf_hi(unsigned u) {
    union { unsigned u; float f; } v; v.u = u & 0xffff0000u; return v.f;
}

// ---------------------------------------------------------------------------
// W1 [20000][512] fp32  ->  Bt [512][20000] bf16 (transpose + convert)
// ---------------------------------------------------------------------------
__global__ __launch_bounds__(256) void transpose_cvt(
    const float* __restrict__ W, unsigned short* __restrict__ out)
{
    __shared__ float tile[32][33];
    const int kb = blockIdx.x * 32;     // 625 blocks
    const int nb = blockIdx.y * 32;     // 16 blocks
    const int tx = threadIdx.x & 31, ty = threadIdx.x >> 5;
#pragma unroll
    for (int i = 0; i < 4; ++i)
        tile[ty + 8 * i][tx] = W[(size_t)(kb + ty + 8 * i) * 512 + nb + tx];
    __syncthreads();
#pragma unroll
    for (int i = 0; i < 4; ++i)
        out[(size_t)(nb + ty + 8 * i) * 20000 + kb + tx] = f2bfr(tile[tx][ty + 8 * i]);
}

// ---------------------------------------------------------------------------
// GEMM1 (MFMA bf16): C += features @ W1.  128x128 tile, BK=32, split-K=5.
// A (fp32) converted to bf16 during staging; Bt is pre-converted bf16 [N][K].
// Grid swizzle: id = z*128 + n*32 + m  -> n-quads of one m-slice share an XCD.
// ---------------------------------------------------------------------------
__global__ __launch_bounds__(256) void gemm1_mfma(
    const float* __restrict__ A,            // [4096][20000] fp32
    const unsigned short* __restrict__ Bt,  // [512][20000] bf16
    float* __restrict__ C)                  // [4096][512] fp32 (zeroed)
{
    __shared__ __align__(16) unsigned short As[128 * 32];
    __shared__ __align__(16) unsigned short Bs[128 * 32];
    const int t = threadIdx.x;
    const int lane = t & 63, w = t >> 6;
    const int id = blockIdx.x;
    const int m0 = (id & 31) * 128;
    const int n0 = ((id >> 5) & 3) * 128;
    const int z  = id >> 7;                 // 0..4, K chunk of 4000

    const int srow = t >> 2, skc = t & 3;   // staging: slot t -> row, k-chunk
    const float*          Ap  = A  + (size_t)(m0 + srow) * 20000 + z * 4000 + skc * 8;
    const float*          Ap2 = Ap + (size_t)64 * 20000;
    const unsigned short* Bp  = Bt + (size_t)(n0 + srow) * 20000 + z * 4000 + skc * 8;
    const unsigned short* Bp2 = Bp + (size_t)64 * 20000;

    const int wr = w >> 1, wc = w & 1;      // wave -> 64x64 quadrant
    const int fr = lane & 15, fq = lane >> 4;

    f32x4 acc[4][4] = {};

    for (int kt = 0; kt < 125; ++kt) {
        const int k0 = kt * 32;
        float4 a0 = *(const float4*)(Ap  + k0);
        float4 a1 = *(const float4*)(Ap  + k0 + 4);
        float4 a2 = *(const float4*)(Ap2 + k0);
        float4 a3 = *(const float4*)(Ap2 + k0 + 4);
        uint4  q0 = *(const uint4*)(Bp  + k0);
        uint4  q1 = *(const uint4*)(Bp2 + k0);
        uint4 p0, p1;
        p0.x = (unsigned)f2bfr(a0.x) | ((unsigned)f2bfr(a0.y) << 16);
        p0.y = (unsigned)f2bfr(a0.z) | ((unsigned)f2bfr(a0.w) << 16);
        p0.z = (unsigned)f2bfr(a1.x) | ((unsigned)f2bfr(a1.y) << 16);
        p0.w = (unsigned)f2bfr(a1.z) | ((unsigned)f2bfr(a1.w) << 16);
        p1.x = (unsigned)f2bfr(a2.x) | ((unsigned)f2bfr(a2.y) << 16);
        p1.y = (unsigned)f2bfr(a2.z) | ((unsigned)f2bfr(a2.w) << 16);
        p1.z = (unsigned)f2bfr(a3.x) | ((unsigned)f2bfr(a3.y) << 16);
        p1.w = (unsigned)f2bfr(a3.z) | ((unsigned)f2bfr(a3.w) << 16);
        *(uint4*)(As + (size_t)t * 8)         = p0;
        *(uint4*)(As + (size_t)(t + 256) * 8) = p1;
        *(uint4*)(Bs + (size_t)t * 8)         = q0;
        *(uint4*)(Bs + (size_t)(t + 256) * 8) = q1;
        __syncthreads();
        bf16x8 af[4], bg[4];
#pragma unroll
        for (int mi = 0; mi < 4; ++mi)
            af[mi] = *(const bf16x8*)(As + (size_t)((wr * 64 + mi * 16 + fr) * 32 + fq * 8));
#pragma unroll
        for (int ni = 0; ni < 4; ++ni)
            bg[ni] = *(const bf16x8*)(Bs + (size_t)((wc * 64 + ni * 16 + fr) * 32 + fq * 8));
#pragma unroll
        for (int mi = 0; mi < 4; ++mi)
#pragma unroll
            for (int ni = 0; ni < 4; ++ni)
                acc[mi][ni] = __builtin_amdgcn_mfma_f32_16x16x32_bf16(
                    af[mi], bg[ni], acc[mi][ni], 0, 0, 0);
        __syncthreads();
    }

    // epilogue: C/D layout col=lane&15, row=(lane>>4)*4+reg
    const int er = fq * 4, ec = fr;
#pragma unroll
    for (int mi = 0; mi < 4; ++mi)
#pragma unroll
    for (int ni = 0; ni < 4; ++ni) {
        const size_t base = (size_t)(m0 + wr * 64 + mi * 16 + er) * 512
                          + n0 + wc * 64 + ni * 16 + ec;
#pragma unroll
        for (int r = 0; r < 4; ++r)
            atomicAdd(&C[base + (size_t)r * 512], acc[mi][ni][r]);
    }
}

// ---------------------------------------------------------------------------
// GEMM2: C = relu( relu(A + b1) @ B + b2 ), 64x64 tile (A = raw gemm1 sums)
// ---------------------------------------------------------------------------
__global__ __launch_bounds__(256) void gemm2_fused(
    const float* __restrict__ A, const float* __restrict__ b1v,
    const float* __restrict__ Bm, const float* __restrict__ bias,
    float* __restrict__ C, int M, int N, int K)
{
    __shared__ float As[16][68];
    __shared__ float Bs[16][64];
    const int t  = threadIdx.x;
    const int tx = t & 15, ty = t >> 4;
    const int m0 = blockIdx.y * 64, n0 = blockIdx.x * 64;

    const int arow = t >> 2;
    const int ak   = (t & 3) << 2;
    const int bk   = t >> 4;
    const int bn   = (t & 15) << 2;

    const float* Aptr = A + (size_t)(m0 + arow) * K + ak;
    const float* Bptr = Bm + (size_t)bk * N + n0 + bn;

    float acc[4][4] = {};

    for (int k0 = 0; k0 < K; k0 += 16) {
        float4 av  = *(const float4*)(Aptr + k0);
        float4 b1q = *(const float4*)(b1v + k0 + ak);
        av.x = fmaxf(av.x + b1q.x, 0.f);
        av.y = fmaxf(av.y + b1q.y, 0.f);
        av.z = fmaxf(av.z + b1q.z, 0.f);
        av.w = fmaxf(av.w + b1q.w, 0.f);
        float4 bv = *(const float4*)(Bptr + (size_t)k0 * N);
        As[ak + 0][arow] = av.x;
        As[ak + 1][arow] = av.y;
        As[ak + 2][arow] = av.z;
        As[ak + 3][arow] = av.w;
        *(float4*)&Bs[bk][bn] = bv;
        __syncthreads();
#pragma unroll
        for (int kk = 0; kk < 16; ++kk) {
            float4 a = *(const float4*)&As[kk][ty << 2];
            float4 b = *(const float4*)&Bs[kk][tx << 2];
            acc[0][0] += a.x * b.x; acc[0][1] += a.x * b.y; acc[0][2] += a.x * b.z; acc[0][3] += a.x * b.w;
            acc[1][0] += a.y * b.x; acc[1][1] += a.y * b.y; acc[1][2] += a.y * b.z; acc[1][3] += a.y * b.w;
            acc[2][0] += a.z * b.x; acc[2][1] += a.z * b.y; acc[2][2] += a.z * b.z; acc[2][3] += a.z * b.w;
            acc[3][0] += a.w * b.x; acc[3][1] += a.w * b.y; acc[3][2] += a.w * b.z; acc[3][3] += a.w * b.w;
        }
        __syncthreads();
    }

    float4 bb = *(const float4*)(bias + n0 + (tx << 2));
#pragma unroll
    for (int i = 0; i < 4; ++i) {
        size_t m = (size_t)m0 + (ty << 2) + i;
        float4 o;
        o.x = fmaxf(acc[i][0] + bb.x, 0.f);
        o.y = fmaxf(acc[i][1] + bb.y, 0.f);
        o.z = fmaxf(acc[i][2] + bb.z, 0.f);
        o.w = fmaxf(acc[i][3] + bb.w, 0.f);
        *(float4*)(C + m * N + n0 + (tx << 2)) = o;
    }
}

// ---------------------------------------------------------------------------
// LayerNorm over 256 features, 1 wave per row, 4 rows per block
// ---------------------------------------------------------------------------
__global__ __launch_bounds__(256) void layernorm256(
    const float* __restrict__ x, const float* __restrict__ g,
    const float* __restrict__ bta, float* __restrict__ y)
{
    const int w = threadIdx.x >> 6, lane = threadIdx.x & 63;
    const size_t row = (size_t)blockIdx.x * 4 + w;
    const float* xr = x + row * 256;
    float4 v = *(const float4*)(xr + lane * 4);
    float s  = v.x + v.y + v.z + v.w;
    float s2 = v.x * v.x + v.y * v.y + v.z * v.z + v.w * v.w;
#pragma unroll
    for (int off = 32; off; off >>= 1) {
        s  += __shfl_down(s, off);
        s2 += __shfl_down(s2, off);
    }
    s  = __shfl(s, 0);
    s2 = __shfl(s2, 0);
    float mu   = s * (1.f / 256.f);
    float var  = s2 * (1.f / 256.f) - mu * mu;
    float rstd = rsqrtf(var + 1e-5f);
    float4 gg = *(const float4*)(g + lane * 4);
    float4 bb = *(const float4*)(bta + lane * 4);
    float4 o;
    o.x = (v.x - mu) * rstd * gg.x + bb.x;
    o.y = (v.y - mu) * rstd * gg.y + bb.y;
    o.z = (v.z - mu) * rstd * gg.z + bb.z;
    o.w = (v.w - mu) * rstd * gg.w + bb.w;
    *(float4*)(y + row * 256 + lane * 4) = o;
}

// ---------------------------------------------------------------------------
// Primary caps: prim[b,n,d] = LN_d( h[b,:] @ pc_W[n,:,d] + pc_b[n,d] ) * g + beta
// ---------------------------------------------------------------------------
__global__ __launch_bounds__(256) void prim_caps(
    const float* __restrict__ h, const float* __restrict__ pcW,
    const float* __restrict__ pcB, const float* __restrict__ pcG,
    const float* __restrict__ pcBeta, float* __restrict__ prim)
{
    __shared__ float hs[256];
    __shared__ float tmp[256];
    const int t = threadIdx.x;
    const size_t b = blockIdx.x;
    hs[t] = h[b * 256 + t];
    __syncthreads();
    const int n = t >> 3, d = t & 7;
    const float* wp = pcW + n * 256 * 8 + d;
    float acc = pcB[t];
#pragma unroll 4
    for (int k = 0; k < 256; ++k) acc += hs[k] * wp[k * 8];
    tmp[t] = acc;
    __syncthreads();
    float mu = 0.f, s2 = 0.f;
    const int base = n << 3;
#pragma unroll
    for (int q = 0; q < 8; ++q) {
        float xx = tmp[base + q];
        mu += xx;
        s2 += xx * xx;
    }
    mu *= 0.125f;
    s2 = s2 * 0.125f - mu * mu;
    float rstd = rsqrtf(s2 + 1e-5f);
    prim[b * 256 + t] = (acc - mu) * rstd * pcG[t] + pcBeta[t];
}

// ---------------------------------------------------------------------------
// Routing, 1 batch row per block, 512 threads. pred materialized ONCE in LDS
// (bf16 pairs, stride 9 words -> conflict-free); b-state fp32 in LDS.
// ---------------------------------------------------------------------------
__global__ __launch_bounds__(512, 1) void routing_b1(
    const float* __restrict__ prim,     // [B,32,8]
    const float* __restrict__ sf,       // [B,100]
    const float* __restrict__ priors,   // [100,100]
    const float* __restrict__ dcW,      // [32,100,16,8]
    const float* __restrict__ targets,  // [100,16]
    const float* __restrict__ temp_p,
    float* __restrict__ out)            // [B,100]
{
    __shared__ float    prim1[256];
    __shared__ unsigned predp[NPC * NJ * 9];   // [n*100+j][op0..7], stride 9: 115200 B
    __shared__ float    bst[NPC * NJ];         // fp32 b-state
    __shared__ float    cst[NPC * NJ];         // softmax coupling c
    __shared__ float    svv[NJ * 18];          // v vectors, stride 18
    __shared__ float    spv[NJ];
    __shared__ float    rmv[NPC], irsv[NPC];
    __shared__ float    red[512];
    __shared__ float    red2[400];
    __shared__ float    ssum;

    const int t = threadIdx.x;
    const int lane = t & 63, w = t >> 6;
    const size_t b = blockIdx.x;

    if (t < 256) prim1[t] = prim[b * 256 + t];
    if (t < 128) red[t] = (t < 100) ? fmaxf(sf[b * 100 + t], 0.f) : 0.f;
    __syncthreads();

    // sum of relu (2 waves reduce)
    if (t < 128) {
        float v = red[t];
#pragma unroll
        for (int d = 32; d; d >>= 1) v += __shfl_xor(v, d);
        if (lane == 0) red[128 + w] = v;
    }
    __syncthreads();
    if (t == 0) ssum = fmaxf(red[128] + red[129], 1e-6f);
    __syncthreads();

    // sp[j] = sum_k (relu_k/ssum - 0.01) * priors[k][j]   (4-way k-split)
    if (t < 400) {
        const int j = t % 100, q = t / 100;
        const float inv = 1.f / ssum;
        float acc = 0.f;
#pragma unroll 5
        for (int k = q * 25; k < q * 25 + 25; ++k)
            acc += (red[k] * inv - 0.01f) * priors[k * 100 + j];
        red2[t] = acc;
    }
    __syncthreads();
    if (t < 100) spv[t] = red2[t] + red2[100 + t] + red2[200 + t] + red2[300 + t];
    __syncthreads();

    // b init
    for (int r = t; r < NPC * NJ; r += 512) bst[r] = spv[r % 100] * 0.1f;

    // ---- pred phase: half-wave (32 lanes) per (n,j) pair; 16 pairs/iter ----
    {
        const int c32  = lane & 31;
        const int half = lane >> 5;
        const int ih   = (c32 & 1) * 4;
#pragma unroll 4
        for (int iter = 0; iter < 200; ++iter) {
            const int p = iter * 16 + w * 2 + half;        // (n,j) pair 0..3199
            const int n = p / 100;
            const float4 wv = *(const float4*)(dcW + (size_t)p * 128 + c32 * 4);
            const float* pb = &prim1[n * 8 + ih];
            float part = wv.x * pb[0] + wv.y * pb[1] + wv.z * pb[2] + wv.w * pb[3];
            float po  = part + __shfl_xor(part, 1);        // pred[o], o=c32>>1
            float po2 = __shfl_xor(po, 2);                 // pred[o+1]
            if ((c32 & 3) == 0)
                predp[p * 9 + (c32 >> 2)] =
                    (unsigned)f2bfr(po) | ((unsigned)f2bfr(po2) << 16);
        }
    }
    __syncthreads();

    // ---- routing iterations ----
    for (int it = 0; it < 3; ++it) {
        // softmax stats per (n): 32 n x 16 lanes
        {
            const int n = t >> 4, q = t & 15;
            float mx = -1e30f;
            for (int j = q; j < 100; j += 16) mx = fmaxf(mx, bst[n * 100 + j]);
#pragma unroll
            for (int d = 1; d < 16; d <<= 1) mx = fmaxf(mx, __shfl_xor(mx, d));
            float se = 0.f;
            for (int j = q; j < 100; j += 16) se += __expf(bst[n * 100 + j] - mx);
#pragma unroll
            for (int d = 1; d < 16; d <<= 1) se += __shfl_xor(se, d);
            if (q == 0) { rmv[n] = mx; irsv[n] = 1.f / se; }
        }
        __syncthreads();
        for (int r = t; r < NPC * NJ; r += 512)
            cst[r] = __expf(bst[r] - rmv[r / 100]) * irsv[r / 100];
        __syncthreads();

        // s-pass + squash: item = (j, op), 800 items
        for (int idx = t; idx < 800; idx += 512) {
            const int j = idx >> 3, op = idx & 7;
            float s0 = 0.f, s1 = 0.f;
#pragma unroll
            for (int n = 0; n < NPC; ++n) {
                const float c = cst[n * 100 + j];
                const unsigned pk = predp[(n * 100 + j) * 9 + op];
                s0 += c * bf_lo(pk);
                s1 += c * bf_hi(pk);
            }
            float sq = s0 * s0 + s1 * s1;
            sq += __shfl_xor(sq, 1);
            sq += __shfl_xor(sq, 2);
            sq += __shfl_xor(sq, 4);
            const float fv = (sq / (1.f + sq)) / sqrtf(sq + 1e-8f);
            svv[j * 18 + op * 2]     = fv * s0;
            svv[j * 18 + op * 2 + 1] = fv * s1;
        }
        __syncthreads();

        // a-pass: b += pred.v + sp*strength
        if (it < 2) {
            const float str = 0.1f - 0.02f * (float)(it + 1);
            for (int r = t; r < NPC * NJ; r += 512) {
                const int j = r % 100;
                float a = 0.f;
#pragma unroll
                for (int op = 0; op < 8; ++op) {
                    const unsigned pk = predp[r * 9 + op];
                    const float2 vv = *(const float2*)&svv[j * 18 + op * 2];
                    a += bf_lo(pk) * vv.x + bf_hi(pk) * vv.y;
                }
                bst[r] += a + spv[j] * str;
            }
            __syncthreads();
        }
    }

    // ---- final: l2norm + logits ----
    if (t < 100) {
        const float T = *temp_p;
        float sq = 0.f, lg = 0.f;
#pragma unroll
        for (int o = 0; o < CD; ++o) {
            const float v = svv[t * 18 + o];
            sq += v * v;
            lg += v * targets[t * CD + o];
        }
        out[b * 100 + t] = lg * T / fmaxf(sqrtf(sq), 1e-12f);
    }
}

// ---------------------------------------------------------------------------
extern "C" void kernel_launch(void* const* d_in, const int* in_sizes, int n_in,
                              void* d_out, int out_size, void* d_ws, size_t ws_size,
                              hipStream_t stream)
{
    const float* features      = (const float*)d_in[0];
    const float* slot_features = (const float*)d_in[1];
    const float* W1            = (const float*)d_in[2];
    const float* b1            = (const float*)d_in[3];
    const float* W2            = (const float*)d_in[4];
    const float* b2            = (const float*)d_in[5];
    const float* ln_g          = (const float*)d_in[6];
    const float* ln_b          = (const float*)d_in[7];
    const float* pc_W          = (const float*)d_in[8];
    const float* pc_b          = (const float*)d_in[9];
    const float* pc_g          = (const float*)d_in[10];
    const float* pc_beta       = (const float*)d_in[11];
    const float* dc_W          = (const float*)d_in[12];
    const float* slot_priors   = (const float*)d_in[13];
    const float* targets       = (const float*)d_in[14];
    const float* temperature   = (const float*)d_in[15];
    float* out = (float*)d_out;

    unsigned short* Bt = (unsigned short*)d_ws;                    // 512*20000 bf16 = 20.48 MB
    float* h1 = (float*)((char*)d_ws + (size_t)512 * 20000 * 2);   // 4096*512
    float* h2 = h1 + (size_t)B_SZ * 512;                           // 4096*256
    float* h  = h2 + (size_t)B_SZ * 256;
    float* pr = h  + (size_t)B_SZ * 256;

    hipMemsetAsync(h1, 0, (size_t)B_SZ * 512 * sizeof(float), stream);

    transpose_cvt<<<dim3(625, 16), 256, 0, stream>>>(W1, Bt);
    gemm1_mfma<<<640, 256, 0, stream>>>(features, Bt, h1);
    gemm2_fused<<<dim3(256 / 64, B_SZ / 64), 256, 0, stream>>>(
        h1, b1, W2, b2, h2, B_SZ, 256, 512);
    layernorm256<<<B_SZ / 4, 256, 0, stream>>>(h2, ln_g, ln_b, h);
    prim_caps<<<B_SZ, 256, 0, stream>>>(h, pc_W, pc_b, pc_g, pc_beta, pr);
    routing_b1<<<B_SZ, 512, 0, stream>>>(
        pr, slot_features, slot_priors, dc_W, targets, temperature, out);
}